// Round 9
// baseline (391.095 us; speedup 1.0000x reference)
//
#include <hip/hip_runtime.h>
#include <hip/hip_bf16.h>

// Problem constants (match reference)
constexpr int B    = 4;
constexpr int N    = 16384;
constexpr int CIN  = 64;
constexpr int COUT = 128;
constexpr int R    = 32;
constexpr int R3   = R * R * R;          // 32768
constexpr int RP   = 34;                 // padded dim
constexpr int RP3  = RP * RP * RP;       // 39304
constexpr int NVOX = B * R3;             // 131072
constexpr float VOX_EPS   = 1e-6f;
constexpr float BN3D_EPS  = 1e-4f;
constexpr float BN1D_EPS  = 1e-5f;
constexpr float LRELU     = 0.1f;

// k_prep block-range partition (exact, no tail checks needed)
constexpr int PREP_ZB = 128;     // zero cntI: 131072*4 B / 4096 B per block
constexpr int PREP_BB = 14739;   // borders: B*6*RP3*4 = 3,773,184 chunks / 256
constexpr int PREP_WB = 2624;    // wq: 164*4096 / 256
constexpr int PREP_SB = 64;      // stats partials: 4 batches x 16 stripes

typedef __attribute__((ext_vector_type(8))) short bf16x8;   // 8 bf16 (4 VGPRs)
typedef __attribute__((ext_vector_type(4))) float f32x4;    // MFMA accumulator
typedef __attribute__((ext_vector_type(8))) unsigned short u16x8;

__device__ inline float bf2f(ushort u) {
    union { unsigned int i; float f; } x; x.i = ((unsigned int)u) << 16; return x.f;
}
__device__ inline ushort f2bf(float f) {   // round-to-nearest-even
    union { float f; unsigned int i; } x; x.f = f;
    unsigned int r = x.i + 0x7fffu + ((x.i >> 16) & 1u);
    return (ushort)(r >> 16);
}

// ---------------------------------------------------------------------------
// CONV LDS LEDGER — CLOSED at R19 (R4 form is the measured optimum of 6):
//   R0 XOR16: 102.0us/40%VALU/7.08M conf | R4 chunk-planar: 96.2/24%/7.08M
//   R6 flat-XOR: 104.4/43%/0 conf — conflict cycles are HIDDEN at 3 blk/CU,
//   the addr math to remove them is VISIBLE. Cheap addressing wins.
// REGISTER WALL (4x confirmed): arch VGPR <= 64, total 128.
// DISPATCH OVERHEAD (R20 measured): ~0.6us/dispatch, NOT ~10. The ~187us
// non-conv time is real kernel time; per-kernel arithmetic pins ~100-130us
// on k_scatter's 4.19M uncoalescable 4B float atomics.
// R21: counting-sort voxelization. atomics 4.19M -> 65K (count pass only);
// fp32 sums buffer + its 34MB zero + the 50MB finalize pass all deleted;
// aggregate sums each voxel's points (wave-uniform loop, coalesced 256B
// feat rows, one read per row) and writes gridp bf16 directly.
// NOTE (R12): do NOT fuse DEPENDENT stages with software grid barriers —
// per-XCD L2 non-coherence makes spin-release ~100us per barrier.
// ---------------------------------------------------------------------------

// stats region (1024 B): [b*8+0..2] = mean xyz, [b*8+3] = max-norm (finals,
// written by k_statsfin); floats [32..224) = per-stripe partial sums.

// nc = clip(((c - mean)/denom + 0.5) * R, 0, R-1)
__device__ inline void compute_nc(const float* __restrict__ coords,
                                  const float* __restrict__ stats,
                                  int p, int b, float& nx, float& ny, float& nz) {
    float denom = stats[b * 8 + 3] * 2.0f + VOX_EPS;
    float cx = coords[(size_t)p * 3 + 0];
    float cy = coords[(size_t)p * 3 + 1];
    float cz = coords[(size_t)p * 3 + 2];
    nx = (cx - stats[b * 8 + 0]) / denom + 0.5f;
    ny = (cy - stats[b * 8 + 1]) / denom + 0.5f;
    nz = (cz - stats[b * 8 + 2]) / denom + 0.5f;
    nx = fminf(fmaxf(nx * (float)R, 0.f), (float)(R - 1));
    ny = fminf(fmaxf(ny * (float)R, 0.f), (float)(R - 1));
    nz = fminf(fmaxf(nz * (float)R, 0.f), (float)(R - 1));
}

// ---------------------------------------------------------------------------
// k_prep: 4 independent fused stages, block-range partitioned.
// ---------------------------------------------------------------------------
__global__ __launch_bounds__(256) void k_prep(const float* __restrict__ coords,
                                              const float* __restrict__ w1,
                                              const float* __restrict__ w2,
                                              const float* __restrict__ pw,
                                              int* __restrict__ cntI,
                                              ushort* __restrict__ borders,
                                              ushort* __restrict__ wq,
                                              float* __restrict__ stats) {
    __shared__ float red[256];
    int blk = blockIdx.x;

    if (blk < PREP_ZB) {   // zero voxel counts (512 KB)
        *(uint4*)((char*)cntI + (((size_t)blk * 256 + threadIdx.x) << 4)) =
            make_uint4(0u, 0u, 0u, 0u);
        return;
    }
    blk -= PREP_ZB;

    if (blk < PREP_BB) {   // border zeroing: i enumerates 16B chunks
        int i = blk * 256 + threadIdx.x;
        int v = i >> 2;
        int r = v % RP3;
        int z = r % RP;
        int t = r / RP;
        int y = t % RP;
        int x = (t / RP) % RP;
        if (x == 0 || x == RP - 1 || y == 0 || y == RP - 1 || z == 0 || z == RP - 1)
            *(uint4*)(borders + (size_t)i * 8) = make_uint4(0u, 0u, 0u, 0u);
        return;
    }
    blk -= PREP_BB;

    if (blk < PREP_WB) {   // weight swizzle, coalesced reads (R19)
        int t = blk * 256 + threadIdx.x;   // < 164*4096
        int g = t >> 12;
        const float* src; int gl;
        if (g < 54)       { src = w1; gl = g; }
        else if (g < 162) { src = w2; gl = g - 54; }
        else              { src = pw; gl = g - 162; }
        int r  = t & 4095;
        int kk = r >> 7;        // 0..31
        int n  = r & 127;       // 0..127
        float v = src[(size_t)(gl * 32 + kk) * COUT + n];
        int idx = g * 4096 + (n >> 4) * 512 + (kk >> 3) * 128 + (n & 15) * 8 + (kk & 7);
        wq[idx] = f2bf(v);
        return;
    }
    blk -= PREP_WB;

    // stats partial sums: blk in [0,64): b = blk>>4, stripe = blk&15
    {
        int b = blk >> 4, stripe = blk & 15;
        const float* c = coords + ((size_t)b * N + stripe * 1024) * 3;
        float sx = 0.f, sy = 0.f, sz = 0.f;
        for (int i = threadIdx.x; i < 1024; i += 256) {
            sx += c[i * 3 + 0];
            sy += c[i * 3 + 1];
            sz += c[i * 3 + 2];
        }
        float vals[3] = {sx, sy, sz};
        for (int k = 0; k < 3; ++k) {
            red[threadIdx.x] = vals[k];
            __syncthreads();
            for (int s = 128; s > 0; s >>= 1) {
                if (threadIdx.x < s) red[threadIdx.x] += red[threadIdx.x + s];
                __syncthreads();
            }
            if (threadIdx.x == 0) stats[32 + (b * 16 + stripe) * 3 + k] = red[0];
            __syncthreads();
        }
    }
}

// ---------------------------------------------------------------------------
// k_statsfin: 4 blocks (one per batch). Mean from stripe partials, then max
// ||c-mean|| (max of squares, sqrt once — monotone). Non-atomic finals.
// ---------------------------------------------------------------------------
__global__ __launch_bounds__(256) void k_statsfin(const float* __restrict__ coords,
                                                  float* __restrict__ stats) {
    int b = blockIdx.x;
    const float invN = 1.0f / (float)N;
    float sx = 0.f, sy = 0.f, sz = 0.f;
    const float* pp = stats + 32 + b * 48;
#pragma unroll
    for (int s = 0; s < 16; ++s) {
        sx += pp[s * 3 + 0];
        sy += pp[s * 3 + 1];
        sz += pp[s * 3 + 2];
    }
    float mx = sx * invN, my = sy * invN, mz = sz * invN;

    const float* c = coords + (size_t)b * N * 3;
    float mm = 0.f;
    for (int i = threadIdx.x; i < N; i += 256) {
        float dx = c[i * 3 + 0] - mx;
        float dy = c[i * 3 + 1] - my;
        float dz = c[i * 3 + 2] - mz;
        mm = fmaxf(mm, dx * dx + dy * dy + dz * dz);
    }
    __shared__ float red[256];
    red[threadIdx.x] = mm;
    __syncthreads();
    for (int s = 128; s > 0; s >>= 1) {
        if (threadIdx.x < s) red[threadIdx.x] = fmaxf(red[threadIdx.x], red[threadIdx.x + s]);
        __syncthreads();
    }
    if (threadIdx.x == 0) {
        stats[b * 8 + 0] = mx;
        stats[b * 8 + 1] = my;
        stats[b * 8 + 2] = mz;
        stats[b * 8 + 3] = sqrtf(red[0]);
    }
}

// ---------------------------------------------------------------------------
// R21 counting-sort voxelization, stage 1: per point, voxel id + ordinal.
// The ONLY atomics in the pipeline (65536, with-return).
// ---------------------------------------------------------------------------
__global__ __launch_bounds__(256) void k_count(const float* __restrict__ coords,
                                               const float* __restrict__ stats,
                                               int* __restrict__ cntI,
                                               int* __restrict__ lin,
                                               int* __restrict__ ord) {
    int p = blockIdx.x * 256 + threadIdx.x;   // < B*N
    int b = p >> 14;
    float nx, ny, nz;
    compute_nc(coords, stats, p, b, nx, ny, nz);
    int vx = (int)rintf(nx);
    int vy = (int)rintf(ny);
    int vz = (int)rintf(nz);
    int l = ((b * R + vx) * R + vy) * R + vz;
    lin[p] = l;
    ord[p] = atomicAdd(&cntI[l], 1);
}

// ---------------------------------------------------------------------------
// Stage 2a: per 1024-bin block, thread owns 4 consecutive bins; LDS exclusive
// scan of 256 thread-sums -> start[] (within-block exclusive), totals[blk].
// ---------------------------------------------------------------------------
__global__ __launch_bounds__(256) void k_scan_a(const int* __restrict__ cntI,
                                                int* __restrict__ startA,
                                                int* __restrict__ totals) {
    __shared__ int s[256];
    int blk = blockIdx.x, t = threadIdx.x;
    int base = blk * 1024 + t * 4;
    int c0 = cntI[base], c1 = cntI[base + 1], c2 = cntI[base + 2], c3 = cntI[base + 3];
    int tsum = c0 + c1 + c2 + c3;
    s[t] = tsum;
    __syncthreads();
    for (int off = 1; off < 256; off <<= 1) {
        int u = (t >= off) ? s[t - off] : 0;
        __syncthreads();
        s[t] += u;
        __syncthreads();
    }
    int excl = s[t] - tsum;
    startA[base + 0] = excl;
    startA[base + 1] = excl + c0;
    startA[base + 2] = excl + c0 + c1;
    startA[base + 3] = excl + c0 + c1 + c2;
    if (t == 255) totals[blk] = s[255];
}

// Stage 2b: 1 block, exclusive scan of the 128 block totals -> bases[].
__global__ __launch_bounds__(128) void k_scan_b(const int* __restrict__ totals,
                                                int* __restrict__ bases) {
    __shared__ int s[128];
    int t = threadIdx.x;
    int v = totals[t];
    s[t] = v;
    __syncthreads();
    for (int off = 1; off < 128; off <<= 1) {
        int u = (t >= off) ? s[t - off] : 0;
        __syncthreads();
        s[t] += u;
        __syncthreads();
    }
    bases[t] = s[t] - v;
}

// Stage 3: place point ids into sorted order. Plain stores, no atomics.
__global__ __launch_bounds__(256) void k_place(const int* __restrict__ lin,
                                               const int* __restrict__ ord,
                                               const int* __restrict__ startA,
                                               const int* __restrict__ bases,
                                               int* __restrict__ sorted) {
    int p = blockIdx.x * 256 + threadIdx.x;   // < B*N
    int l = lin[p];
    int pos = bases[l >> 10] + startA[l] + ord[p];
    sorted[pos] = p;
}

// ---------------------------------------------------------------------------
// Stage 4: aggregate + finalize fused. Wave handles 16 consecutive voxels;
// cnt is wave-uniform -> non-divergent point loop; lane ci sums feats[p][ci]
// (coalesced 256B row per iteration, each feat row read exactly once).
// Writes gridp (padded planar [B][2][34][34][34][32]) = sum / max(cnt,1).
// ---------------------------------------------------------------------------
__global__ __launch_bounds__(256) void k_aggregate(const float* __restrict__ feats,
                                                   const int* __restrict__ cntI,
                                                   const int* __restrict__ startA,
                                                   const int* __restrict__ bases,
                                                   const int* __restrict__ sorted,
                                                   ushort* __restrict__ gridp) {
    int wave = threadIdx.x >> 6, ci = threadIdx.x & 63;
    int vbase = (blockIdx.x * 4 + wave) * 16;    // 2048 blocks -> 131072 voxels
#pragma unroll 1
    for (int j = 0; j < 16; ++j) {
        int v = vbase + j;
        int c = cntI[v];
        int st = bases[v >> 10] + startA[v];
        float acc = 0.f;
        for (int k = 0; k < c; ++k) {
            int p = sorted[st + k];
            acc += feats[(size_t)p * CIN + ci];
        }
        float val = acc / (float)(c == 0 ? 1 : c);
        int vz = v & 31, vy = (v >> 5) & 31, vx = (v >> 10) & 31, b = v >> 15;
        size_t o = ((((size_t)(b * 2 + (ci >> 5)) * RP + vx + 1) * RP + vy + 1) * RP
                    + vz + 1) * 32 + (ci & 31);
        gridp[o] = f2bf(val);
    }
}

// ---------------------------------------------------------------------------
// MFMA implicit-GEMM 3x3x3 conv + bias + BN + LeakyReLU.  (R4-verified form,
// the measured optimum of 6 LDS variants — see ledger at top.)
// Input: padded channel-planar [B][CI/32][34][34][34][32] bf16 (borders zero).
// Block = 256 thr (4 waves 2x2): tile M=128 (4 y-columns), N=128.
// LDS slab chunk-planar [18 rows][4 ch][34 z], no swizzle. ~4 cyc/read bank
// conflict (7.08M/dispatch) hidden at 3 blocks/CU — tolerated by design.
// Tap loop: single-loop form (do NOT unroll dz / hoist B-loads — VGPR).
// REGISTER BUDGET (hard): arch VGPR <= 64. acc[4][4] = 64 AGPRs; 64+64=128
// = exactly 4 waves/SIMD. __launch_bounds__(256,3): do NOT raise to 4 (R5).
// ---------------------------------------------------------------------------
template <int CI, bool PLANAR_OUT>
__global__ __launch_bounds__(256, 3) void k_conv_mfma(const ushort* __restrict__ in,
                                                      const ushort* __restrict__ wq,
                                                      const float* __restrict__ bias,
                                                      const float* __restrict__ bng,
                                                      const float* __restrict__ bnb,
                                                      const float* __restrict__ bnm,
                                                      const float* __restrict__ bnv,
                                                      ushort* __restrict__ out) {
    constexpr int NCHI = CI / 32;
    __shared__ __align__(16) ushort sl[18 * 4 * 34 * 8];   // 39168 B

    int bid = blockIdx.x;
    int Y = bid & 7;                  // y-group (4 columns)
    int x = (bid >> 3) & 31;
    int b = bid >> 8;
    int y0 = Y * 4;
    int tid = threadIdx.x;
    int wave = tid >> 6, lane = tid & 63, quad = lane >> 4, l16 = lane & 15;
    int wm = wave >> 1, wn = wave & 1;

    f32x4 acc[4][4] = {};   // [m-tile][n-tile]

    for (int cc = 0; cc < NCHI; ++cc) {
        const ushort* base = in + (((size_t)(b * NCHI + cc) * RP + x) * RP + y0) * RP * 32;
        __syncthreads();
        for (int t = tid; t < 18 * 136; t += 256) {
            int row = t / 136;               // 0..17 = X*6 + Yl
            int r   = t - row * 136;         // 0..135: z = r>>2, ch = r&3
            int X = row / 6, Yl = row - X * 6;
            uint4 v = *(const uint4*)(base + ((size_t)(X * RP + Yl) * RP) * 32 + r * 8);
            int z = r >> 2, ch = r & 3;
            *(uint4*)(sl + ((row * 4 + ch) * 34 + z) * 8) = v;
        }
        __syncthreads();

        for (int tap = 0; tap < 27; ++tap) {
            int dx = tap / 9, rem = tap - dx * 9;
            int dy = rem / 3, dz = rem - dy * 3;

            const ushort* bp = wq + ((size_t)((tap * NCHI + cc) * 8 + wn * 4) * 64 + lane) * 8;
            bf16x8 bfr[4], afr[4];
#pragma unroll
            for (int nt = 0; nt < 4; ++nt)
                bfr[nt] = *(const bf16x8*)(bp + nt * 512);
#pragma unroll
            for (int mt = 0; mt < 4; ++mt) {
                int row18 = dx * 6 + wm * 2 + (mt >> 1) + dy;
                int zrow = ((mt & 1) << 4) + l16 + dz;
                afr[mt] = *(const bf16x8*)(sl + (((row18 * 4 + quad) * 34) + zrow) * 8);
            }
#pragma unroll
            for (int mt = 0; mt < 4; ++mt)
#pragma unroll
                for (int nt = 0; nt < 4; ++nt)
                    acc[mt][nt] = __builtin_amdgcn_mfma_f32_16x16x32_bf16(
                        afr[mt], bfr[nt], acc[mt][nt], 0, 0, 0);
        }
    }

    // Epilogue. C/D layout: col = lane&15 (cout), row = quad*4 + reg (m).
    float sc[4], sb[4], bs[4];
#pragma unroll
    for (int nt = 0; nt < 4; ++nt) {
        int co = wn * 64 + nt * 16 + l16;
        sc[nt] = bng[co] * rsqrtf(bnv[co] + BN3D_EPS);
        sb[nt] = bnb[co] - bnm[co] * sc[nt];
        bs[nt] = bias[co];
    }
#pragma unroll
    for (int mt = 0; mt < 4; ++mt) {
#pragma unroll
        for (int reg = 0; reg < 4; ++reg) {
            int m = wm * 64 + mt * 16 + quad * 4 + reg;
            int i = m >> 5, z = m & 31;
#pragma unroll
            for (int nt = 0; nt < 4; ++nt) {
                float v = (acc[mt][nt][reg] + bs[nt]) * sc[nt] + sb[nt];
                v = v >= 0.f ? v : LRELU * v;
                int co = wn * 64 + nt * 16 + l16;
                if (PLANAR_OUT) {
                    // out planar padded [B][4][34][34][34][32]
                    size_t o = ((((size_t)(b * 4 + (co >> 5)) * RP + (x + 1)) * RP
                                 + (y0 + i + 1)) * RP + (z + 1)) * 32 + (co & 31);
                    out[o] = f2bf(v);
                } else {
                    size_t o = (((size_t)(b * R + x) * R + (y0 + i)) * R + z) * COUT + co;
                    out[o] = f2bf(v);
                }
            }
        }
    }
}

// ---------------------------------------------------------------------------
// Devoxelize + point MLP, two phases. Block = 128 points, 256 thr.
// R19: sfeat/smlp UNIONED in one 32KB pool (sfeat dead after phase-1 reads).
// Tail: coords passthrough copy folded in.
// ---------------------------------------------------------------------------
__global__ __launch_bounds__(256, 3) void k_devox(const float* __restrict__ coords,
                                                  const float* __restrict__ feats,
                                                  const float* __restrict__ stats,
                                                  const ushort* __restrict__ g2,
                                                  const ushort* __restrict__ pwq,
                                                  const float* __restrict__ pb,
                                                  const float* __restrict__ pg,
                                                  const float* __restrict__ pbb,
                                                  const float* __restrict__ pm,
                                                  const float* __restrict__ pv,
                                                  float* __restrict__ out) {
    __shared__ __align__(16) ushort spool[128 * 128];  // sfeat (16KB) ∪ smlp (32KB)
    __shared__ int   sidx[128 * 8];
    __shared__ float swt[128 * 8];

    int blk = blockIdx.x, tid = threadIdx.x;
    int wave = tid >> 6, lane = tid & 63, quad = lane >> 4, l16 = lane & 15;
    int p0 = blk * 128;

    if (tid < 128) {
        int p = p0 + tid, b = p >> 14;
        float nx, ny, nz;
        compute_nc(coords, stats, p, b, nx, ny, nz);
        int cx0 = (int)floorf(nx), cy0 = (int)floorf(ny), cz0 = (int)floorf(nz);
        float fx = nx - (float)cx0, fy = ny - (float)cy0, fz = nz - (float)cz0;
        int cx1 = min(cx0 + 1, R - 1), cy1 = min(cy0 + 1, R - 1), cz1 = min(cz0 + 1, R - 1);
#pragma unroll
        for (int k = 0; k < 8; ++k) {
            int dx = (k >> 2) & 1, dy = (k >> 1) & 1, dz = k & 1;
            int ix = dx ? cx1 : cx0;
            int iy = dy ? cy1 : cy0;
            int iz = dz ? cz1 : cz0;
            sidx[tid * 8 + k] = (((b * R + ix) * R + iy) * R + iz) * COUT;
            swt[tid * 8 + k] = (dx ? fx : 1.f - fx) * (dy ? fy : 1.f - fy) * (dz ? fz : 1.f - fz);
        }
    }
    // stage feats -> bf16 LDS [128p][64ci], 16B-chunk swizzle phys = ch ^ (p&7)
    for (int i = 0; i < 4; ++i) {
        int c = i * 256 + tid;          // 0..1023
        int p = c >> 3, ch = c & 7;
        const float* src = feats + (size_t)(p0 + p) * CIN + ch * 8;
        float4 f0 = *(const float4*)src;
        float4 f1 = *(const float4*)(src + 4);
        u16x8 u;
        u[0] = f2bf(f0.x); u[1] = f2bf(f0.y); u[2] = f2bf(f0.z); u[3] = f2bf(f0.w);
        u[4] = f2bf(f1.x); u[5] = f2bf(f1.y); u[6] = f2bf(f1.z); u[7] = f2bf(f1.w);
        *(u16x8*)&spool[(p * 8 + (ch ^ (p & 7))) * 8] = u;
    }
    __syncthreads();

    // Phase 1: MLP MFMA. pwq groups live at offset 162*4096 in merged wq.
    f32x4 acc[8][2] = {};
#pragma unroll
    for (int cc = 0; cc < 2; ++cc) {
        const ushort* bp = pwq + ((size_t)(cc * 8 + wave * 2) * 64 + lane) * 8;
        bf16x8 b0 = *(const bf16x8*)bp;
        bf16x8 b1 = *(const bf16x8*)(bp + 512);
#pragma unroll
        for (int mt = 0; mt < 8; ++mt) {
            int prow = mt * 16 + l16;
            int ch = cc * 4 + quad;
            bf16x8 a = *(const bf16x8*)&spool[(prow * 8 + (ch ^ (prow & 7))) * 8];
            acc[mt][0] = __builtin_amdgcn_mfma_f32_16x16x32_bf16(a, b0, acc[mt][0], 0, 0, 0);
            acc[mt][1] = __builtin_amdgcn_mfma_f32_16x16x32_bf16(a, b1, acc[mt][1], 0, 0, 0);
        }
    }
    __syncthreads();   // all sfeat reads done — pool may be rewritten as smlp

    int co0 = wave * 32 + l16, co1 = co0 + 16;
    {
        float sc0 = pg[co0] * rsqrtf(pv[co0] + BN1D_EPS);
        float sb0 = pbb[co0] - pm[co0] * sc0;
        float bs0 = pb[co0];
        float sc1 = pg[co1] * rsqrtf(pv[co1] + BN1D_EPS);
        float sb1 = pbb[co1] - pm[co1] * sc1;
        float bs1 = pb[co1];
#pragma unroll
        for (int mt = 0; mt < 8; ++mt) {
#pragma unroll
            for (int reg = 0; reg < 4; ++reg) {
                int pl = mt * 16 + quad * 4 + reg;
                spool[pl * 128 + co0] = f2bf(fmaxf((acc[mt][0][reg] + bs0) * sc0 + sb0, 0.f));
                spool[pl * 128 + co1] = f2bf(fmaxf((acc[mt][1][reg] + bs1) * sc1 + sb1, 0.f));
            }
        }
    }
    __syncthreads();

    // Phase 2: vectorized gather + blend. task = (point p, chunk c of 8 couts)
#pragma unroll
    for (int it = 0; it < 8; ++it) {
        int t = it * 256 + tid;          // 0..2047
        int p = t >> 4, c = t & 15;
        float a[8];
        const ushort* m = &spool[p * 128 + c * 8];
#pragma unroll
        for (int j = 0; j < 8; ++j) a[j] = bf2f(m[j]);
#pragma unroll
        for (int k = 0; k < 8; ++k) {
            int idx = sidx[p * 8 + k];
            float w = swt[p * 8 + k];
            bf16x8 row = *(const bf16x8*)(g2 + (size_t)idx + c * 8);
#pragma unroll
            for (int j = 0; j < 8; ++j) a[j] += w * bf2f(((u16x8)row)[j]);
        }
        float* o = out + (size_t)(p0 + p) * COUT + c * 8;
        *(float4*)o       = make_float4(a[0], a[1], a[2], a[3]);
        *(float4*)(o + 4) = make_float4(a[4], a[5], a[6], a[7]);
    }

    // coords passthrough (output 1), grid-stride over 512 blocks
    {
        float* dst = out + (size_t)B * N * COUT;
        for (int i = blk * 256 + tid; i < B * N * 3; i += 512 * 256)
            dst[i] = coords[i];
    }
}

// ---------------------------------------------------------------------------
extern "C" void kernel_launch(void* const* d_in, const int* in_sizes, int n_in,
                              void* d_out, int out_size, void* d_ws, size_t ws_size,
                              hipStream_t stream) {
    const float* feats   = (const float*)d_in[0];
    const float* coords  = (const float*)d_in[1];
    const float* conv1_w = (const float*)d_in[2];
    const float* conv1_b = (const float*)d_in[3];
    const float* bn1_g   = (const float*)d_in[4];
    const float* bn1_b   = (const float*)d_in[5];
    const float* bn1_m   = (const float*)d_in[6];
    const float* bn1_v   = (const float*)d_in[7];
    const float* conv2_w = (const float*)d_in[8];
    const float* conv2_b = (const float*)d_in[9];
    const float* bn2_g   = (const float*)d_in[10];
    const float* bn2_b   = (const float*)d_in[11];
    const float* bn2_m   = (const float*)d_in[12];
    const float* bn2_v   = (const float*)d_in[13];
    const float* pw      = (const float*)d_in[14];
    const float* pb      = (const float*)d_in[15];
    const float* pbn_g   = (const float*)d_in[16];
    const float* pbn_b   = (const float*)d_in[17];
    const float* pbn_m   = (const float*)d_in[18];
    const float* pbn_v   = (const float*)d_in[19];

    // Workspace layout
    char* p = (char*)d_ws;
    float* stats  = (float*)p;                       p += 1024;
    int*   cntI   = (int*)p;                         p += (size_t)NVOX * 4;
    int*   lin    = (int*)p;                         p += (size_t)B * N * 4;
    int*   ord    = (int*)p;                         p += (size_t)B * N * 4;
    int*   sorted = (int*)p;                         p += (size_t)B * N * 4;
    int*   startA = (int*)p;                         p += (size_t)NVOX * 4;
    int*   totals = (int*)p;                         p += 1024;
    int*   bases  = (int*)p;                         p += 1024;
    ushort* gridp = (ushort*)p;                      p += (size_t)B * 2 * RP3 * 32 * 2;
    ushort* g1p   = (ushort*)p;                      p += (size_t)B * 4 * RP3 * 32 * 2;
    ushort* g2b   = (ushort*)p;                      p += (size_t)B * R3 * COUT * 2;
    ushort* wq    = (ushort*)p;                      p += (size_t)164 * 4096 * 2;
    ushort* wq1 = wq;
    ushort* wq2 = wq + 54 * 4096;
    ushort* pwq = wq + 162 * 4096;
    float*  outf  = (float*)d_out;

    // 10 dispatches (R21; ~0.6us each measured R20)
    k_prep<<<PREP_ZB + PREP_BB + PREP_WB + PREP_SB, 256, 0, stream>>>(
        coords, conv1_w, conv2_w, pw, cntI, gridp, wq, stats);
    k_statsfin<<<4, 256, 0, stream>>>(coords, stats);
    k_count<<<(B * N) / 256, 256, 0, stream>>>(coords, stats, cntI, lin, ord);
    k_scan_a<<<NVOX / 1024, 256, 0, stream>>>(cntI, startA, totals);
    k_scan_b<<<1, 128, 0, stream>>>(totals, bases);
    k_place<<<(B * N) / 256, 256, 0, stream>>>(lin, ord, startA, bases, sorted);
    k_aggregate<<<NVOX / 64, 256, 0, stream>>>(feats, cntI, startA, bases, sorted, gridp);

    k_conv_mfma<CIN, true><<<B * R * (R / 4), 256, 0, stream>>>(
        gridp, wq1, conv1_b, bn1_g, bn1_b, bn1_m, bn1_v, g1p);
    k_conv_mfma<COUT, false><<<B * R * (R / 4), 256, 0, stream>>>(
        g1p, wq2, conv2_b, bn2_g, bn2_b, bn2_m, bn2_v, g2b);

    k_devox<<<(B * N) / 128, 256, 0, stream>>>(coords, feats, stats, g2b, pwq, pb,
                                               pbn_g, pbn_b, pbn_m, pbn_v, outf);
}

// Round 10
// 347.222 us; speedup vs baseline: 1.1264x; 1.1264x over previous
//
#include <hip/hip_runtime.h>
#include <hip/hip_bf16.h>

// Problem constants (match reference)
constexpr int B    = 4;
constexpr int N    = 16384;
constexpr int CIN  = 64;
constexpr int COUT = 128;
constexpr int R    = 32;
constexpr int R3   = R * R * R;          // 32768
constexpr int RP   = 34;                 // padded dim
constexpr int RP3  = RP * RP * RP;       // 39304
constexpr int NVOX = B * R3;             // 131072
constexpr float VOX_EPS   = 1e-6f;
constexpr float BN3D_EPS  = 1e-4f;
constexpr float BN1D_EPS  = 1e-5f;
constexpr float LRELU     = 0.1f;

// k_prep block-range partition (exact, no tail checks needed)
constexpr int PREP_ZB = 128;     // zero cntI: 131072*4 B / 4096 B per block
constexpr int PREP_BB = 14739;   // borders: B*6*RP3*4 = 3,773,184 chunks / 256
constexpr int PREP_WB = 2624;    // wq: 164*4096 / 256
constexpr int PREP_SB = 64;      // stats partials: 4 batches x 16 stripes

typedef __attribute__((ext_vector_type(8))) short bf16x8;   // 8 bf16 (4 VGPRs)
typedef __attribute__((ext_vector_type(4))) float f32x4;    // MFMA accumulator
typedef __attribute__((ext_vector_type(8))) unsigned short u16x8;

__device__ inline float bf2f(ushort u) {
    union { unsigned int i; float f; } x; x.i = ((unsigned int)u) << 16; return x.f;
}
__device__ inline ushort f2bf(float f) {   // round-to-nearest-even
    union { float f; unsigned int i; } x; x.f = f;
    unsigned int r = x.i + 0x7fffu + ((x.i >> 16) & 1u);
    return (ushort)(r >> 16);
}

// ---------------------------------------------------------------------------
// CONV LDS LEDGER — CLOSED at R19 (R4 form is the measured optimum of 6).
// REGISTER WALL (4x confirmed): arch VGPR <= 64, total 128.
// DISPATCH OVERHEAD (R20 measured): ~0.6us/dispatch.
// R21 counting-sort: atomics 4.19M -> 65K; sums+finalize deleted.
// R22 (this round): k_aggregate was 101-128us LATENCY-BOUND (VALUBusy 5%,
// occ 10.5% — 16 voxels SERIAL per wave, ~1.5k-cycle dependent chains, only
// 8K chains in flight). Fix: ONE WAVE PER VOXEL (131K independent chains,
// 16-deep TLP per wave slot) — same traffic, latency hidden. Measured note:
// old scatter+finalize was ~60-85us (R8 accounting via R9 delta), so the
// sort pipeline must come in well under that to pay.
// NOTE (R12): do NOT fuse DEPENDENT stages with software grid barriers —
// per-XCD L2 non-coherence makes spin-release ~100us per barrier.
// ---------------------------------------------------------------------------

// stats region (1024 B): [b*8+0..2] = mean xyz, [b*8+3] = max-norm (finals,
// written by k_statsfin); floats [32..224) = per-stripe partial sums.

// nc = clip(((c - mean)/denom + 0.5) * R, 0, R-1)
__device__ inline void compute_nc(const float* __restrict__ coords,
                                  const float* __restrict__ stats,
                                  int p, int b, float& nx, float& ny, float& nz) {
    float denom = stats[b * 8 + 3] * 2.0f + VOX_EPS;
    float cx = coords[(size_t)p * 3 + 0];
    float cy = coords[(size_t)p * 3 + 1];
    float cz = coords[(size_t)p * 3 + 2];
    nx = (cx - stats[b * 8 + 0]) / denom + 0.5f;
    ny = (cy - stats[b * 8 + 1]) / denom + 0.5f;
    nz = (cz - stats[b * 8 + 2]) / denom + 0.5f;
    nx = fminf(fmaxf(nx * (float)R, 0.f), (float)(R - 1));
    ny = fminf(fmaxf(ny * (float)R, 0.f), (float)(R - 1));
    nz = fminf(fmaxf(nz * (float)R, 0.f), (float)(R - 1));
}

// ---------------------------------------------------------------------------
// k_prep: 4 independent fused stages, block-range partitioned.
// ---------------------------------------------------------------------------
__global__ __launch_bounds__(256) void k_prep(const float* __restrict__ coords,
                                              const float* __restrict__ w1,
                                              const float* __restrict__ w2,
                                              const float* __restrict__ pw,
                                              int* __restrict__ cntI,
                                              ushort* __restrict__ borders,
                                              ushort* __restrict__ wq,
                                              float* __restrict__ stats) {
    __shared__ float red[256];
    int blk = blockIdx.x;

    if (blk < PREP_ZB) {   // zero voxel counts (512 KB)
        *(uint4*)((char*)cntI + (((size_t)blk * 256 + threadIdx.x) << 4)) =
            make_uint4(0u, 0u, 0u, 0u);
        return;
    }
    blk -= PREP_ZB;

    if (blk < PREP_BB) {   // border zeroing: i enumerates 16B chunks
        int i = blk * 256 + threadIdx.x;
        int v = i >> 2;
        int r = v % RP3;
        int z = r % RP;
        int t = r / RP;
        int y = t % RP;
        int x = (t / RP) % RP;
        if (x == 0 || x == RP - 1 || y == 0 || y == RP - 1 || z == 0 || z == RP - 1)
            *(uint4*)(borders + (size_t)i * 8) = make_uint4(0u, 0u, 0u, 0u);
        return;
    }
    blk -= PREP_BB;

    if (blk < PREP_WB) {   // weight swizzle, coalesced reads (R19)
        int t = blk * 256 + threadIdx.x;   // < 164*4096
        int g = t >> 12;
        const float* src; int gl;
        if (g < 54)       { src = w1; gl = g; }
        else if (g < 162) { src = w2; gl = g - 54; }
        else              { src = pw; gl = g - 162; }
        int r  = t & 4095;
        int kk = r >> 7;        // 0..31
        int n  = r & 127;       // 0..127
        float v = src[(size_t)(gl * 32 + kk) * COUT + n];
        int idx = g * 4096 + (n >> 4) * 512 + (kk >> 3) * 128 + (n & 15) * 8 + (kk & 7);
        wq[idx] = f2bf(v);
        return;
    }
    blk -= PREP_WB;

    // stats partial sums: blk in [0,64): b = blk>>4, stripe = blk&15
    {
        int b = blk >> 4, stripe = blk & 15;
        const float* c = coords + ((size_t)b * N + stripe * 1024) * 3;
        float sx = 0.f, sy = 0.f, sz = 0.f;
        for (int i = threadIdx.x; i < 1024; i += 256) {
            sx += c[i * 3 + 0];
            sy += c[i * 3 + 1];
            sz += c[i * 3 + 2];
        }
        float vals[3] = {sx, sy, sz};
        for (int k = 0; k < 3; ++k) {
            red[threadIdx.x] = vals[k];
            __syncthreads();
            for (int s = 128; s > 0; s >>= 1) {
                if (threadIdx.x < s) red[threadIdx.x] += red[threadIdx.x + s];
                __syncthreads();
            }
            if (threadIdx.x == 0) stats[32 + (b * 16 + stripe) * 3 + k] = red[0];
            __syncthreads();
        }
    }
}

// ---------------------------------------------------------------------------
// k_statsfin: 4 blocks (one per batch). Mean from stripe partials, then max
// ||c-mean|| (max of squares, sqrt once — monotone). Non-atomic finals.
// ---------------------------------------------------------------------------
__global__ __launch_bounds__(256) void k_statsfin(const float* __restrict__ coords,
                                                  float* __restrict__ stats) {
    int b = blockIdx.x;
    const float invN = 1.0f / (float)N;
    float sx = 0.f, sy = 0.f, sz = 0.f;
    const float* pp = stats + 32 + b * 48;
#pragma unroll
    for (int s = 0; s < 16; ++s) {
        sx += pp[s * 3 + 0];
        sy += pp[s * 3 + 1];
        sz += pp[s * 3 + 2];
    }
    float mx = sx * invN, my = sy * invN, mz = sz * invN;

    const float* c = coords + (size_t)b * N * 3;
    float mm = 0.f;
    for (int i = threadIdx.x; i < N; i += 256) {
        float dx = c[i * 3 + 0] - mx;
        float dy = c[i * 3 + 1] - my;
        float dz = c[i * 3 + 2] - mz;
        mm = fmaxf(mm, dx * dx + dy * dy + dz * dz);
    }
    __shared__ float red[256];
    red[threadIdx.x] = mm;
    __syncthreads();
    for (int s = 128; s > 0; s >>= 1) {
        if (threadIdx.x < s) red[threadIdx.x] = fmaxf(red[threadIdx.x], red[threadIdx.x + s]);
        __syncthreads();
    }
    if (threadIdx.x == 0) {
        stats[b * 8 + 0] = mx;
        stats[b * 8 + 1] = my;
        stats[b * 8 + 2] = mz;
        stats[b * 8 + 3] = sqrtf(red[0]);
    }
}

// ---------------------------------------------------------------------------
// Counting-sort stage 1: per point, voxel id + ordinal (only atomics left).
// ---------------------------------------------------------------------------
__global__ __launch_bounds__(256) void k_count(const float* __restrict__ coords,
                                               const float* __restrict__ stats,
                                               int* __restrict__ cntI,
                                               int* __restrict__ lin,
                                               int* __restrict__ ord) {
    int p = blockIdx.x * 256 + threadIdx.x;   // < B*N
    int b = p >> 14;
    float nx, ny, nz;
    compute_nc(coords, stats, p, b, nx, ny, nz);
    int vx = (int)rintf(nx);
    int vy = (int)rintf(ny);
    int vz = (int)rintf(nz);
    int l = ((b * R + vx) * R + vy) * R + vz;
    lin[p] = l;
    ord[p] = atomicAdd(&cntI[l], 1);
}

// ---------------------------------------------------------------------------
// Stage 2a: per 1024-bin block, thread owns 4 consecutive bins; LDS exclusive
// scan of 256 thread-sums -> start[] (within-block exclusive), totals[blk].
// ---------------------------------------------------------------------------
__global__ __launch_bounds__(256) void k_scan_a(const int* __restrict__ cntI,
                                                int* __restrict__ startA,
                                                int* __restrict__ totals) {
    __shared__ int s[256];
    int blk = blockIdx.x, t = threadIdx.x;
    int base = blk * 1024 + t * 4;
    int c0 = cntI[base], c1 = cntI[base + 1], c2 = cntI[base + 2], c3 = cntI[base + 3];
    int tsum = c0 + c1 + c2 + c3;
    s[t] = tsum;
    __syncthreads();
    for (int off = 1; off < 256; off <<= 1) {
        int u = (t >= off) ? s[t - off] : 0;
        __syncthreads();
        s[t] += u;
        __syncthreads();
    }
    int excl = s[t] - tsum;
    startA[base + 0] = excl;
    startA[base + 1] = excl + c0;
    startA[base + 2] = excl + c0 + c1;
    startA[base + 3] = excl + c0 + c1 + c2;
    if (t == 255) totals[blk] = s[255];
}

// Stage 2b: 1 block, exclusive scan of the 128 block totals -> bases[].
__global__ __launch_bounds__(128) void k_scan_b(const int* __restrict__ totals,
                                                int* __restrict__ bases) {
    __shared__ int s[128];
    int t = threadIdx.x;
    int v = totals[t];
    s[t] = v;
    __syncthreads();
    for (int off = 1; off < 128; off <<= 1) {
        int u = (t >= off) ? s[t - off] : 0;
        __syncthreads();
        s[t] += u;
        __syncthreads();
    }
    bases[t] = s[t] - v;
}

// Stage 3: place point ids into sorted order. Plain stores, no atomics.
__global__ __launch_bounds__(256) void k_place(const int* __restrict__ lin,
                                               const int* __restrict__ ord,
                                               const int* __restrict__ startA,
                                               const int* __restrict__ bases,
                                               int* __restrict__ sorted) {
    int p = blockIdx.x * 256 + threadIdx.x;   // < B*N
    int l = lin[p];
    int pos = bases[l >> 10] + startA[l] + ord[p];
    sorted[pos] = p;
}

// ---------------------------------------------------------------------------
// Stage 4 (R22): aggregate + finalize fused, ONE WAVE PER VOXEL.
// 131072 independent latency chains (vs R21's 8192 chains of 16 serial
// voxels — that was 101-128us, VALUBusy 5%, occ 10%). Lane ci sums
// feats[p][ci] (coalesced 256B row per point, each row read exactly once),
// divides, writes gridp (padded planar [B][2][34][34][34][32]) bf16.
// ---------------------------------------------------------------------------
__global__ __launch_bounds__(256) void k_aggregate(const float* __restrict__ feats,
                                                   const int* __restrict__ cntI,
                                                   const int* __restrict__ startA,
                                                   const int* __restrict__ bases,
                                                   const int* __restrict__ sorted,
                                                   ushort* __restrict__ gridp) {
    int wave = threadIdx.x >> 6, ci = threadIdx.x & 63;
    int v = blockIdx.x * 4 + wave;               // 32768 blocks -> 131072 voxels
    int c = cntI[v];
    int st = bases[v >> 10] + startA[v];
    float acc = 0.f;
    for (int k = 0; k < c; ++k) {
        int p = sorted[st + k];
        acc += feats[(size_t)p * CIN + ci];
    }
    float val = acc / (float)(c == 0 ? 1 : c);
    int vz = v & 31, vy = (v >> 5) & 31, vx = (v >> 10) & 31, b = v >> 15;
    size_t o = ((((size_t)(b * 2 + (ci >> 5)) * RP + vx + 1) * RP + vy + 1) * RP
                + vz + 1) * 32 + (ci & 31);
    gridp[o] = f2bf(val);
}

// ---------------------------------------------------------------------------
// MFMA implicit-GEMM 3x3x3 conv + bias + BN + LeakyReLU.  (R4-verified form,
// the measured optimum of 6 LDS variants.)
// LDS slab chunk-planar [18 rows][4 ch][34 z], no swizzle. ~4 cyc/read bank
// conflict (7.08M/dispatch) hidden at 3 blocks/CU — tolerated by design.
// Tap loop: single-loop form (do NOT unroll dz / hoist B-loads — VGPR).
// REGISTER BUDGET (hard): arch VGPR <= 64. acc[4][4] = 64 AGPRs; 64+64=128
// = exactly 4 waves/SIMD. __launch_bounds__(256,3): do NOT raise to 4 (R5).
// ---------------------------------------------------------------------------
template <int CI, bool PLANAR_OUT>
__global__ __launch_bounds__(256, 3) void k_conv_mfma(const ushort* __restrict__ in,
                                                      const ushort* __restrict__ wq,
                                                      const float* __restrict__ bias,
                                                      const float* __restrict__ bng,
                                                      const float* __restrict__ bnb,
                                                      const float* __restrict__ bnm,
                                                      const float* __restrict__ bnv,
                                                      ushort* __restrict__ out) {
    constexpr int NCHI = CI / 32;
    __shared__ __align__(16) ushort sl[18 * 4 * 34 * 8];   // 39168 B

    int bid = blockIdx.x;
    int Y = bid & 7;                  // y-group (4 columns)
    int x = (bid >> 3) & 31;
    int b = bid >> 8;
    int y0 = Y * 4;
    int tid = threadIdx.x;
    int wave = tid >> 6, lane = tid & 63, quad = lane >> 4, l16 = lane & 15;
    int wm = wave >> 1, wn = wave & 1;

    f32x4 acc[4][4] = {};   // [m-tile][n-tile]

    for (int cc = 0; cc < NCHI; ++cc) {
        const ushort* base = in + (((size_t)(b * NCHI + cc) * RP + x) * RP + y0) * RP * 32;
        __syncthreads();
        for (int t = tid; t < 18 * 136; t += 256) {
            int row = t / 136;               // 0..17 = X*6 + Yl
            int r   = t - row * 136;         // 0..135: z = r>>2, ch = r&3
            int X = row / 6, Yl = row - X * 6;
            uint4 v = *(const uint4*)(base + ((size_t)(X * RP + Yl) * RP) * 32 + r * 8);
            int z = r >> 2, ch = r & 3;
            *(uint4*)(sl + ((row * 4 + ch) * 34 + z) * 8) = v;
        }
        __syncthreads();

        for (int tap = 0; tap < 27; ++tap) {
            int dx = tap / 9, rem = tap - dx * 9;
            int dy = rem / 3, dz = rem - dy * 3;

            const ushort* bp = wq + ((size_t)((tap * NCHI + cc) * 8 + wn * 4) * 64 + lane) * 8;
            bf16x8 bfr[4], afr[4];
#pragma unroll
            for (int nt = 0; nt < 4; ++nt)
                bfr[nt] = *(const bf16x8*)(bp + nt * 512);
#pragma unroll
            for (int mt = 0; mt < 4; ++mt) {
                int row18 = dx * 6 + wm * 2 + (mt >> 1) + dy;
                int zrow = ((mt & 1) << 4) + l16 + dz;
                afr[mt] = *(const bf16x8*)(sl + (((row18 * 4 + quad) * 34) + zrow) * 8);
            }
#pragma unroll
            for (int mt = 0; mt < 4; ++mt)
#pragma unroll
                for (int nt = 0; nt < 4; ++nt)
                    acc[mt][nt] = __builtin_amdgcn_mfma_f32_16x16x32_bf16(
                        afr[mt], bfr[nt], acc[mt][nt], 0, 0, 0);
        }
    }

    // Epilogue. C/D layout: col = lane&15 (cout), row = quad*4 + reg (m).
    float sc[4], sb[4], bs[4];
#pragma unroll
    for (int nt = 0; nt < 4; ++nt) {
        int co = wn * 64 + nt * 16 + l16;
        sc[nt] = bng[co] * rsqrtf(bnv[co] + BN3D_EPS);
        sb[nt] = bnb[co] - bnm[co] * sc[nt];
        bs[nt] = bias[co];
    }
#pragma unroll
    for (int mt = 0; mt < 4; ++mt) {
#pragma unroll
        for (int reg = 0; reg < 4; ++reg) {
            int m = wm * 64 + mt * 16 + quad * 4 + reg;
            int i = m >> 5, z = m & 31;
#pragma unroll
            for (int nt = 0; nt < 4; ++nt) {
                float v = (acc[mt][nt][reg] + bs[nt]) * sc[nt] + sb[nt];
                v = v >= 0.f ? v : LRELU * v;
                int co = wn * 64 + nt * 16 + l16;
                if (PLANAR_OUT) {
                    // out planar padded [B][4][34][34][34][32]
                    size_t o = ((((size_t)(b * 4 + (co >> 5)) * RP + (x + 1)) * RP
                                 + (y0 + i + 1)) * RP + (z + 1)) * 32 + (co & 31);
                    out[o] = f2bf(v);
                } else {
                    size_t o = (((size_t)(b * R + x) * R + (y0 + i)) * R + z) * COUT + co;
                    out[o] = f2bf(v);
                }
            }
        }
    }
}

// ---------------------------------------------------------------------------
// Devoxelize + point MLP, two phases. Block = 128 points, 256 thr.
// R19: sfeat/smlp UNIONED in one 32KB pool (sfeat dead after phase-1 reads).
// Tail: coords passthrough copy folded in.
// ---------------------------------------------------------------------------
__global__ __launch_bounds__(256, 3) void k_devox(const float* __restrict__ coords,
                                                  const float* __restrict__ feats,
                                                  const float* __restrict__ stats,
                                                  const ushort* __restrict__ g2,
                                                  const ushort* __restrict__ pwq,
                                                  const float* __restrict__ pb,
                                                  const float* __restrict__ pg,
                                                  const float* __restrict__ pbb,
                                                  const float* __restrict__ pm,
                                                  const float* __restrict__ pv,
                                                  float* __restrict__ out) {
    __shared__ __align__(16) ushort spool[128 * 128];  // sfeat (16KB) ∪ smlp (32KB)
    __shared__ int   sidx[128 * 8];
    __shared__ float swt[128 * 8];

    int blk = blockIdx.x, tid = threadIdx.x;
    int wave = tid >> 6, lane = tid & 63, quad = lane >> 4, l16 = lane & 15;
    int p0 = blk * 128;

    if (tid < 128) {
        int p = p0 + tid, b = p >> 14;
        float nx, ny, nz;
        compute_nc(coords, stats, p, b, nx, ny, nz);
        int cx0 = (int)floorf(nx), cy0 = (int)floorf(ny), cz0 = (int)floorf(nz);
        float fx = nx - (float)cx0, fy = ny - (float)cy0, fz = nz - (float)cz0;
        int cx1 = min(cx0 + 1, R - 1), cy1 = min(cy0 + 1, R - 1), cz1 = min(cz0 + 1, R - 1);
#pragma unroll
        for (int k = 0; k < 8; ++k) {
            int dx = (k >> 2) & 1, dy = (k >> 1) & 1, dz = k & 1;
            int ix = dx ? cx1 : cx0;
            int iy = dy ? cy1 : cy0;
            int iz = dz ? cz1 : cz0;
            sidx[tid * 8 + k] = (((b * R + ix) * R + iy) * R + iz) * COUT;
            swt[tid * 8 + k] = (dx ? fx : 1.f - fx) * (dy ? fy : 1.f - fy) * (dz ? fz : 1.f - fz);
        }
    }
    // stage feats -> bf16 LDS [128p][64ci], 16B-chunk swizzle phys = ch ^ (p&7)
    for (int i = 0; i < 4; ++i) {
        int c = i * 256 + tid;          // 0..1023
        int p = c >> 3, ch = c & 7;
        const float* src = feats + (size_t)(p0 + p) * CIN + ch * 8;
        float4 f0 = *(const float4*)src;
        float4 f1 = *(const float4*)(src + 4);
        u16x8 u;
        u[0] = f2bf(f0.x); u[1] = f2bf(f0.y); u[2] = f2bf(f0.z); u[3] = f2bf(f0.w);
        u[4] = f2bf(f1.x); u[5] = f2bf(f1.y); u[6] = f2bf(f1.z); u[7] = f2bf(f1.w);
        *(u16x8*)&spool[(p * 8 + (ch ^ (p & 7))) * 8] = u;
    }
    __syncthreads();

    // Phase 1: MLP MFMA. pwq groups live at offset 162*4096 in merged wq.
    f32x4 acc[8][2] = {};
#pragma unroll
    for (int cc = 0; cc < 2; ++cc) {
        const ushort* bp = pwq + ((size_t)(cc * 8 + wave * 2) * 64 + lane) * 8;
        bf16x8 b0 = *(const bf16x8*)bp;
        bf16x8 b1 = *(const bf16x8*)(bp + 512);
#pragma unroll
        for (int mt = 0; mt < 8; ++mt) {
            int prow = mt * 16 + l16;
            int ch = cc * 4 + quad;
            bf16x8 a = *(const bf16x8*)&spool[(prow * 8 + (ch ^ (prow & 7))) * 8];
            acc[mt][0] = __builtin_amdgcn_mfma_f32_16x16x32_bf16(a, b0, acc[mt][0], 0, 0, 0);
            acc[mt][1] = __builtin_amdgcn_mfma_f32_16x16x32_bf16(a, b1, acc[mt][1], 0, 0, 0);
        }
    }
    __syncthreads();   // all sfeat reads done — pool may be rewritten as smlp

    int co0 = wave * 32 + l16, co1 = co0 + 16;
    {
        float sc0 = pg[co0] * rsqrtf(pv[co0] + BN1D_EPS);
        float sb0 = pbb[co0] - pm[co0] * sc0;
        float bs0 = pb[co0];
        float sc1 = pg[co1] * rsqrtf(pv[co1] + BN1D_EPS);
        float sb1 = pbb[co1] - pm[co1] * sc1;
        float bs1 = pb[co1];
#pragma unroll
        for (int mt = 0; mt < 8; ++mt) {
#pragma unroll
            for (int reg = 0; reg < 4; ++reg) {
                int pl = mt * 16 + quad * 4 + reg;
                spool[pl * 128 + co0] = f2bf(fmaxf((acc[mt][0][reg] + bs0) * sc0 + sb0, 0.f));
                spool[pl * 128 + co1] = f2bf(fmaxf((acc[mt][1][reg] + bs1) * sc1 + sb1, 0.f));
            }
        }
    }
    __syncthreads();

    // Phase 2: vectorized gather + blend. task = (point p, chunk c of 8 couts)
#pragma unroll
    for (int it = 0; it < 8; ++it) {
        int t = it * 256 + tid;          // 0..2047
        int p = t >> 4, c = t & 15;
        float a[8];
        const ushort* m = &spool[p * 128 + c * 8];
#pragma unroll
        for (int j = 0; j < 8; ++j) a[j] = bf2f(m[j]);
#pragma unroll
        for (int k = 0; k < 8; ++k) {
            int idx = sidx[p * 8 + k];
            float w = swt[p * 8 + k];
            bf16x8 row = *(const bf16x8*)(g2 + (size_t)idx + c * 8);
#pragma unroll
            for (int j = 0; j < 8; ++j) a[j] += w * bf2f(((u16x8)row)[j]);
        }
        float* o = out + (size_t)(p0 + p) * COUT + c * 8;
        *(float4*)o       = make_float4(a[0], a[1], a[2], a[3]);
        *(float4*)(o + 4) = make_float4(a[4], a[5], a[6], a[7]);
    }

    // coords passthrough (output 1), grid-stride over 512 blocks
    {
        float* dst = out + (size_t)B * N * COUT;
        for (int i = blk * 256 + tid; i < B * N * 3; i += 512 * 256)
            dst[i] = coords[i];
    }
}

// ---------------------------------------------------------------------------
extern "C" void kernel_launch(void* const* d_in, const int* in_sizes, int n_in,
                              void* d_out, int out_size, void* d_ws, size_t ws_size,
                              hipStream_t stream) {
    const float* feats   = (const float*)d_in[0];
    const float* coords  = (const float*)d_in[1];
    const float* conv1_w = (const float*)d_in[2];
    const float* conv1_b = (const float*)d_in[3];
    const float* bn1_g   = (const float*)d_in[4];
    const float* bn1_b   = (const float*)d_in[5];
    const float* bn1_m   = (const float*)d_in[6];
    const float* bn1_v   = (const float*)d_in[7];
    const float* conv2_w = (const float*)d_in[8];
    const float* conv2_b = (const float*)d_in[9];
    const float* bn2_g   = (const float*)d_in[10];
    const float* bn2_b   = (const float*)d_in[11];
    const float* bn2_m   = (const float*)d_in[12];
    const float* bn2_v   = (const float*)d_in[13];
    const float* pw      = (const float*)d_in[14];
    const float* pb      = (const float*)d_in[15];
    const float* pbn_g   = (const float*)d_in[16];
    const float* pbn_b   = (const float*)d_in[17];
    const float* pbn_m   = (const float*)d_in[18];
    const float* pbn_v   = (const float*)d_in[19];

    // Workspace layout
    char* p = (char*)d_ws;
    float* stats  = (float*)p;                       p += 1024;
    int*   cntI   = (int*)p;                         p += (size_t)NVOX * 4;
    int*   lin    = (int*)p;                         p += (size_t)B * N * 4;
    int*   ord    = (int*)p;                         p += (size_t)B * N * 4;
    int*   sorted = (int*)p;                         p += (size_t)B * N * 4;
    int*   startA = (int*)p;                         p += (size_t)NVOX * 4;
    int*   totals = (int*)p;                         p += 1024;
    int*   bases  = (int*)p;                         p += 1024;
    ushort* gridp = (ushort*)p;                      p += (size_t)B * 2 * RP3 * 32 * 2;
    ushort* g1p   = (ushort*)p;                      p += (size_t)B * 4 * RP3 * 32 * 2;
    ushort* g2b   = (ushort*)p;                      p += (size_t)B * R3 * COUT * 2;
    ushort* wq    = (ushort*)p;                      p += (size_t)164 * 4096 * 2;
    ushort* wq1 = wq;
    ushort* wq2 = wq + 54 * 4096;
    ushort* pwq = wq + 162 * 4096;
    float*  outf  = (float*)d_out;

    // 10 dispatches (~0.6us each measured R20)
    k_prep<<<PREP_ZB + PREP_BB + PREP_WB + PREP_SB, 256, 0, stream>>>(
        coords, conv1_w, conv2_w, pw, cntI, gridp, wq, stats);
    k_statsfin<<<4, 256, 0, stream>>>(coords, stats);
    k_count<<<(B * N) / 256, 256, 0, stream>>>(coords, stats, cntI, lin, ord);
    k_scan_a<<<NVOX / 1024, 256, 0, stream>>>(cntI, startA, totals);
    k_scan_b<<<1, 128, 0, stream>>>(totals, bases);
    k_place<<<(B * N) / 256, 256, 0, stream>>>(lin, ord, startA, bases, sorted);
    k_aggregate<<<NVOX / 4, 256, 0, stream>>>(feats, cntI, startA, bases, sorted, gridp);

    k_conv_mfma<CIN, true><<<B * R * (R / 4), 256, 0, stream>>>(
        gridp, wq1, conv1_b, bn1_g, bn1_b, bn1_m, bn1_v, g1p);
    k_conv_mfma<COUT, false><<<B * R * (R / 4), 256, 0, stream>>>(
        g1p, wq2, conv2_b, bn2_g, bn2_b, bn2_m, bn2_v, g2b);

    k_devox<<<(B * N) / 128, 256, 0, stream>>>(coords, feats, stats, g2b, pwq, pb,
                                               pbn_g, pbn_b, pbn_m, pbn_v, outf);
}

// Round 12
// 333.246 us; speedup vs baseline: 1.1736x; 1.0419x over previous
//
#include <hip/hip_runtime.h>
#include <hip/hip_bf16.h>

// Problem constants (match reference)
constexpr int B    = 4;
constexpr int N    = 16384;
constexpr int CIN  = 64;
constexpr int COUT = 128;
constexpr int R    = 32;
constexpr int R3   = R * R * R;          // 32768
constexpr int RP   = 34;                 // padded dim
constexpr int RP3  = RP * RP * RP;       // 39304
constexpr float VOX_EPS   = 1e-6f;
constexpr float BN3D_EPS  = 1e-4f;
constexpr float BN1D_EPS  = 1e-5f;
constexpr float LRELU     = 0.1f;

// k_prep block-range partition (exact, no tail checks needed)
constexpr int PREP_ZB = 8320;    // zero sums+cnt: 34,078,720 B / 4096 B per block
constexpr int PREP_BB = 14739;   // borders: B*6*RP3*4 = 3,773,184 chunks / 256
constexpr int PREP_WB = 2624;    // wq: 164*4096 / 256
constexpr int PREP_SB = 64;      // stats partials: 4 batches x 16 stripes

typedef __attribute__((ext_vector_type(8))) short bf16x8;   // 8 bf16 (4 VGPRs)
typedef __attribute__((ext_vector_type(4))) float f32x4;    // MFMA accumulator
typedef __attribute__((ext_vector_type(8))) unsigned short u16x8;

__device__ inline float bf2f(ushort u) {
    union { unsigned int i; float f; } x; x.i = ((unsigned int)u) << 16; return x.f;
}
__device__ inline ushort f2bf(float f) {   // round-to-nearest-even
    union { float f; unsigned int i; } x; x.f = f;
    unsigned int r = x.i + 0x7fffu + ((x.i >> 16) & 1u);
    return (ushort)(r >> 16);
}

// ---------------------------------------------------------------------------
// CONV LDS LEDGER — CLOSED at R19 (R4 form is the measured optimum of 6).
// REGISTER WALL (4x confirmed): arch VGPR <= 64, total 128.
// DISPATCH OVERHEAD (R20 measured): ~0.6us/dispatch.
// VOXELIZATION LEDGER — CLOSED at R23: counting-sort = 347us total vs
// scatter+finalize = 330.8us; atomics were never the dominant sink.
// DEVOX-SPLIT FROZEN (R24): the 64-pt/block devox (R23 proposal) FAILED
// correctness with no bug found by full index re-derivation (absmax still
// 0.015625 — localized mismatch). Do NOT retry without a local repro.
// The proven devox is the 128-pt/512-block form below.
// R24: k_scatter barrier-removal — per-lane redundant nc (wave-uniform),
// no LDS broadcast, no __syncthreads; lane 0 does the cnt atomic. Waves
// issue their atomic bursts independently.
// NOTE (R12): do NOT fuse DEPENDENT stages with software grid barriers —
// per-XCD L2 non-coherence makes spin-release ~100us per barrier.
// ---------------------------------------------------------------------------

// stats region (1024 B): [b*8+0..2] = mean xyz, [b*8+3] = max-norm (finals,
// written by k_statsfin); floats [32..224) = per-stripe partial sums.

// nc = clip(((c - mean)/denom + 0.5) * R, 0, R-1)
__device__ inline void compute_nc(const float* __restrict__ coords,
                                  const float* __restrict__ stats,
                                  int p, int b, float& nx, float& ny, float& nz) {
    float denom = stats[b * 8 + 3] * 2.0f + VOX_EPS;
    float cx = coords[(size_t)p * 3 + 0];
    float cy = coords[(size_t)p * 3 + 1];
    float cz = coords[(size_t)p * 3 + 2];
    nx = (cx - stats[b * 8 + 0]) / denom + 0.5f;
    ny = (cy - stats[b * 8 + 1]) / denom + 0.5f;
    nz = (cz - stats[b * 8 + 2]) / denom + 0.5f;
    nx = fminf(fmaxf(nx * (float)R, 0.f), (float)(R - 1));
    ny = fminf(fmaxf(ny * (float)R, 0.f), (float)(R - 1));
    nz = fminf(fmaxf(nz * (float)R, 0.f), (float)(R - 1));
}

// ---------------------------------------------------------------------------
// k_prep: 4 independent fused stages, block-range partitioned.
// ---------------------------------------------------------------------------
__global__ __launch_bounds__(256) void k_prep(const float* __restrict__ coords,
                                              const float* __restrict__ w1,
                                              const float* __restrict__ w2,
                                              const float* __restrict__ pw,
                                              float* __restrict__ zbase,
                                              ushort* __restrict__ borders,
                                              ushort* __restrict__ wq,
                                              float* __restrict__ stats) {
    __shared__ float red[256];
    int blk = blockIdx.x;

    if (blk < PREP_ZB) {   // zero sums+cnt (34 MB)
        *(uint4*)((char*)zbase + (((size_t)blk * 256 + threadIdx.x) << 4)) =
            make_uint4(0u, 0u, 0u, 0u);
        return;
    }
    blk -= PREP_ZB;

    if (blk < PREP_BB) {   // border zeroing: i enumerates 16B chunks
        int i = blk * 256 + threadIdx.x;
        int v = i >> 2;
        int r = v % RP3;
        int z = r % RP;
        int t = r / RP;
        int y = t % RP;
        int x = (t / RP) % RP;
        if (x == 0 || x == RP - 1 || y == 0 || y == RP - 1 || z == 0 || z == RP - 1)
            *(uint4*)(borders + (size_t)i * 8) = make_uint4(0u, 0u, 0u, 0u);
        return;
    }
    blk -= PREP_BB;

    if (blk < PREP_WB) {   // weight swizzle, coalesced reads (R19)
        int t = blk * 256 + threadIdx.x;   // < 164*4096
        int g = t >> 12;
        const float* src; int gl;
        if (g < 54)       { src = w1; gl = g; }
        else if (g < 162) { src = w2; gl = g - 54; }
        else              { src = pw; gl = g - 162; }
        int r  = t & 4095;
        int kk = r >> 7;        // 0..31
        int n  = r & 127;       // 0..127
        float v = src[(size_t)(gl * 32 + kk) * COUT + n];
        int idx = g * 4096 + (n >> 4) * 512 + (kk >> 3) * 128 + (n & 15) * 8 + (kk & 7);
        wq[idx] = f2bf(v);
        return;
    }
    blk -= PREP_WB;

    // stats partial sums: blk in [0,64): b = blk>>4, stripe = blk&15
    {
        int b = blk >> 4, stripe = blk & 15;
        const float* c = coords + ((size_t)b * N + stripe * 1024) * 3;
        float sx = 0.f, sy = 0.f, sz = 0.f;
        for (int i = threadIdx.x; i < 1024; i += 256) {
            sx += c[i * 3 + 0];
            sy += c[i * 3 + 1];
            sz += c[i * 3 + 2];
        }
        float vals[3] = {sx, sy, sz};
        for (int k = 0; k < 3; ++k) {
            red[threadIdx.x] = vals[k];
            __syncthreads();
            for (int s = 128; s > 0; s >>= 1) {
                if (threadIdx.x < s) red[threadIdx.x] += red[threadIdx.x + s];
                __syncthreads();
            }
            if (threadIdx.x == 0) stats[32 + (b * 16 + stripe) * 3 + k] = red[0];
            __syncthreads();
        }
    }
}

// ---------------------------------------------------------------------------
// k_statsfin: 4 blocks (one per batch). Mean from stripe partials, then max
// ||c-mean|| (max of squares, sqrt once — monotone). Non-atomic finals.
// ---------------------------------------------------------------------------
__global__ __launch_bounds__(256) void k_statsfin(const float* __restrict__ coords,
                                                  float* __restrict__ stats) {
    int b = blockIdx.x;
    const float invN = 1.0f / (float)N;
    float sx = 0.f, sy = 0.f, sz = 0.f;
    const float* pp = stats + 32 + b * 48;
#pragma unroll
    for (int s = 0; s < 16; ++s) {
        sx += pp[s * 3 + 0];
        sy += pp[s * 3 + 1];
        sz += pp[s * 3 + 2];
    }
    float mx = sx * invN, my = sy * invN, mz = sz * invN;

    const float* c = coords + (size_t)b * N * 3;
    float mm = 0.f;
    for (int i = threadIdx.x; i < N; i += 256) {
        float dx = c[i * 3 + 0] - mx;
        float dy = c[i * 3 + 1] - my;
        float dz = c[i * 3 + 2] - mz;
        mm = fmaxf(mm, dx * dx + dy * dy + dz * dz);
    }
    __shared__ float red[256];
    red[threadIdx.x] = mm;
    __syncthreads();
    for (int s = 128; s > 0; s >>= 1) {
        if (threadIdx.x < s) red[threadIdx.x] = fmaxf(red[threadIdx.x], red[threadIdx.x + s]);
        __syncthreads();
    }
    if (threadIdx.x == 0) {
        stats[b * 8 + 0] = mx;
        stats[b * 8 + 1] = my;
        stats[b * 8 + 2] = mz;
        stats[b * 8 + 3] = sqrtf(red[0]);
    }
}

// ---------------------------------------------------------------------------
// Scatter-add features into fp32 sums + counts (4 points / block).
// R24: barrier-free. All 64 lanes of a wave share sub -> per-lane nc math is
// wave-uniform (broadcast loads); no LDS, no __syncthreads. Lane 0 does the
// cnt atomic. Waves issue atomic bursts independently.
// ---------------------------------------------------------------------------
__global__ __launch_bounds__(256) void k_scatter(const float* __restrict__ coords,
                                                 const float* __restrict__ feats,
                                                 const float* __restrict__ stats,
                                                 float* __restrict__ sums,
                                                 float* __restrict__ cnt) {
    int sub = threadIdx.x >> 6;        // 0..3
    int ci  = threadIdx.x & 63;
    int p   = blockIdx.x * 4 + sub;    // point index 0..B*N
    int b = p >> 14;                   // N = 16384
    float nx, ny, nz;
    compute_nc(coords, stats, p, b, nx, ny, nz);
    int vx = (int)rintf(nx);
    int vy = (int)rintf(ny);
    int vz = (int)rintf(nz);
    int lin = ((b * R + vx) * R + vy) * R + vz;
    if (ci == 0) atomicAdd(&cnt[lin], 1.0f);
    atomicAdd(&sums[(size_t)lin * CIN + ci], feats[(size_t)p * CIN + ci]);
}

// ---------------------------------------------------------------------------
// gridp(bf16, padded planar [B][2][34][34][34][32]) = sums / max(cnt,1)
// ---------------------------------------------------------------------------
__global__ __launch_bounds__(256) void k_finalize(const float* __restrict__ sums,
                                                  const float* __restrict__ cnt,
                                                  ushort* __restrict__ gridp) {
    int i = blockIdx.x * 256 + threadIdx.x;   // B*R3*CIN total
    float c = cnt[i >> 6];
    float val = sums[i] / (c == 0.f ? 1.f : c);
    int ci = i & 63;
    int v = i >> 6;
    int vz = v & 31, vy = (v >> 5) & 31, vx = (v >> 10) & 31, b = v >> 15;
    size_t o = ((((size_t)(b * 2 + (ci >> 5)) * RP + vx + 1) * RP + vy + 1) * RP + vz + 1) * 32
               + (ci & 31);
    gridp[o] = f2bf(val);
}

// ---------------------------------------------------------------------------
// MFMA implicit-GEMM 3x3x3 conv + bias + BN + LeakyReLU.  (R4-verified form,
// the measured optimum of 6 LDS variants.)
// LDS slab chunk-planar [18 rows][4 ch][34 z], no swizzle. ~4 cyc/read bank
// conflict (7.08M/dispatch) hidden at 3 blocks/CU — tolerated by design.
// Tap loop: single-loop form (do NOT unroll dz / hoist B-loads — VGPR).
// REGISTER BUDGET (hard): arch VGPR <= 64. acc[4][4] = 64 AGPRs; 64+64=128
// = exactly 4 waves/SIMD. __launch_bounds__(256,3): do NOT raise to 4 (R5).
// ---------------------------------------------------------------------------
template <int CI, bool PLANAR_OUT>
__global__ __launch_bounds__(256, 3) void k_conv_mfma(const ushort* __restrict__ in,
                                                      const ushort* __restrict__ wq,
                                                      const float* __restrict__ bias,
                                                      const float* __restrict__ bng,
                                                      const float* __restrict__ bnb,
                                                      const float* __restrict__ bnm,
                                                      const float* __restrict__ bnv,
                                                      ushort* __restrict__ out) {
    constexpr int NCHI = CI / 32;
    __shared__ __align__(16) ushort sl[18 * 4 * 34 * 8];   // 39168 B

    int bid = blockIdx.x;
    int Y = bid & 7;                  // y-group (4 columns)
    int x = (bid >> 3) & 31;
    int b = bid >> 8;
    int y0 = Y * 4;
    int tid = threadIdx.x;
    int wave = tid >> 6, lane = tid & 63, quad = lane >> 4, l16 = lane & 15;
    int wm = wave >> 1, wn = wave & 1;

    f32x4 acc[4][4] = {};   // [m-tile][n-tile]

    for (int cc = 0; cc < NCHI; ++cc) {
        const ushort* base = in + (((size_t)(b * NCHI + cc) * RP + x) * RP + y0) * RP * 32;
        __syncthreads();
        for (int t = tid; t < 18 * 136; t += 256) {
            int row = t / 136;               // 0..17 = X*6 + Yl
            int r   = t - row * 136;         // 0..135: z = r>>2, ch = r&3
            int X = row / 6, Yl = row - X * 6;
            uint4 v = *(const uint4*)(base + ((size_t)(X * RP + Yl) * RP) * 32 + r * 8);
            int z = r >> 2, ch = r & 3;
            *(uint4*)(sl + ((row * 4 + ch) * 34 + z) * 8) = v;
        }
        __syncthreads();

        for (int tap = 0; tap < 27; ++tap) {
            int dx = tap / 9, rem = tap - dx * 9;
            int dy = rem / 3, dz = rem - dy * 3;

            const ushort* bp = wq + ((size_t)((tap * NCHI + cc) * 8 + wn * 4) * 64 + lane) * 8;
            bf16x8 bfr[4], afr[4];
#pragma unroll
            for (int nt = 0; nt < 4; ++nt)
                bfr[nt] = *(const bf16x8*)(bp + nt * 512);
#pragma unroll
            for (int mt = 0; mt < 4; ++mt) {
                int row18 = dx * 6 + wm * 2 + (mt >> 1) + dy;
                int zrow = ((mt & 1) << 4) + l16 + dz;
                afr[mt] = *(const bf16x8*)(sl + (((row18 * 4 + quad) * 34) + zrow) * 8);
            }
#pragma unroll
            for (int mt = 0; mt < 4; ++mt)
#pragma unroll
                for (int nt = 0; nt < 4; ++nt)
                    acc[mt][nt] = __builtin_amdgcn_mfma_f32_16x16x32_bf16(
                        afr[mt], bfr[nt], acc[mt][nt], 0, 0, 0);
        }
    }

    // Epilogue. C/D layout: col = lane&15 (cout), row = quad*4 + reg (m).
    float sc[4], sb[4], bs[4];
#pragma unroll
    for (int nt = 0; nt < 4; ++nt) {
        int co = wn * 64 + nt * 16 + l16;
        sc[nt] = bng[co] * rsqrtf(bnv[co] + BN3D_EPS);
        sb[nt] = bnb[co] - bnm[co] * sc[nt];
        bs[nt] = bias[co];
    }
#pragma unroll
    for (int mt = 0; mt < 4; ++mt) {
#pragma unroll
        for (int reg = 0; reg < 4; ++reg) {
            int m = wm * 64 + mt * 16 + quad * 4 + reg;
            int i = m >> 5, z = m & 31;
#pragma unroll
            for (int nt = 0; nt < 4; ++nt) {
                float v = (acc[mt][nt][reg] + bs[nt]) * sc[nt] + sb[nt];
                v = v >= 0.f ? v : LRELU * v;
                int co = wn * 64 + nt * 16 + l16;
                if (PLANAR_OUT) {
                    // out planar padded [B][4][34][34][34][32]
                    size_t o = ((((size_t)(b * 4 + (co >> 5)) * RP + (x + 1)) * RP
                                 + (y0 + i + 1)) * RP + (z + 1)) * 32 + (co & 31);
                    out[o] = f2bf(v);
                } else {
                    size_t o = (((size_t)(b * R + x) * R + (y0 + i)) * R + z) * COUT + co;
                    out[o] = f2bf(v);
                }
            }
        }
    }
}

// ---------------------------------------------------------------------------
// Devoxelize + point MLP, two phases. Block = 128 points, 256 thr.
// (R8-proven form — devox-split frozen per R24 ledger.)
// Phase 1: point MLP via MFMA (pwq read once/block) -> bf16 LDS [128p][128co].
// Phase 2: task = (point, 8-cout chunk): 8 corner rows gathered as bf16x8
// (16B) loads, weighted-summed with the MLP result, stored as coalesced f32.
// R19: sfeat/smlp UNIONED in one 32KB pool (sfeat dead after phase-1 reads;
// barrier separates). LDS 56KB -> 40KB.
// Tail: coords passthrough copy folded in (saves the memcpy graph node).
// ---------------------------------------------------------------------------
__global__ __launch_bounds__(256, 3) void k_devox(const float* __restrict__ coords,
                                                  const float* __restrict__ feats,
                                                  const float* __restrict__ stats,
                                                  const ushort* __restrict__ g2,
                                                  const ushort* __restrict__ pwq,
                                                  const float* __restrict__ pb,
                                                  const float* __restrict__ pg,
                                                  const float* __restrict__ pbb,
                                                  const float* __restrict__ pm,
                                                  const float* __restrict__ pv,
                                                  float* __restrict__ out) {
    __shared__ __align__(16) ushort spool[128 * 128];  // sfeat (16KB) ∪ smlp (32KB)
    __shared__ int   sidx[128 * 8];
    __shared__ float swt[128 * 8];

    int blk = blockIdx.x, tid = threadIdx.x;
    int wave = tid >> 6, lane = tid & 63, quad = lane >> 4, l16 = lane & 15;
    int p0 = blk * 128;

    if (tid < 128) {
        int p = p0 + tid, b = p >> 14;
        float nx, ny, nz;
        compute_nc(coords, stats, p, b, nx, ny, nz);
        int cx0 = (int)floorf(nx), cy0 = (int)floorf(ny), cz0 = (int)floorf(nz);
        float fx = nx - (float)cx0, fy = ny - (float)cy0, fz = nz - (float)cz0;
        int cx1 = min(cx0 + 1, R - 1), cy1 = min(cy0 + 1, R - 1), cz1 = min(cz0 + 1, R - 1);
#pragma unroll
        for (int k = 0; k < 8; ++k) {
            int dx = (k >> 2) & 1, dy = (k >> 1) & 1, dz = k & 1;
            int ix = dx ? cx1 : cx0;
            int iy = dy ? cy1 : cy0;
            int iz = dz ? cz1 : cz0;
            sidx[tid * 8 + k] = (((b * R + ix) * R + iy) * R + iz) * COUT;
            swt[tid * 8 + k] = (dx ? fx : 1.f - fx) * (dy ? fy : 1.f - fy) * (dz ? fz : 1.f - fz);
        }
    }
    // stage feats -> bf16 LDS [128p][64ci], 16B-chunk swizzle phys = ch ^ (p&7)
    for (int i = 0; i < 4; ++i) {
        int c = i * 256 + tid;          // 0..1023
        int p = c >> 3, ch = c & 7;
        const float* src = feats + (size_t)(p0 + p) * CIN + ch * 8;
        float4 f0 = *(const float4*)src;
        float4 f1 = *(const float4*)(src + 4);
        u16x8 u;
        u[0] = f2bf(f0.x); u[1] = f2bf(f0.y); u[2] = f2bf(f0.z); u[3] = f2bf(f0.w);
        u[4] = f2bf(f1.x); u[5] = f2bf(f1.y); u[6] = f2bf(f1.z); u[7] = f2bf(f1.w);
        *(u16x8*)&spool[(p * 8 + (ch ^ (p & 7))) * 8] = u;
    }
    __syncthreads();

    // Phase 1: MLP MFMA. pwq groups live at offset 162*4096 in merged wq.
    f32x4 acc[8][2] = {};
#pragma unroll
    for (int cc = 0; cc < 2; ++cc) {
        const ushort* bp = pwq + ((size_t)(cc * 8 + wave * 2) * 64 + lane) * 8;
        bf16x8 b0 = *(const bf16x8*)bp;
        bf16x8 b1 = *(const bf16x8*)(bp + 512);
#pragma unroll
        for (int mt = 0; mt < 8; ++mt) {
            int prow = mt * 16 + l16;
            int ch = cc * 4 + quad;
            bf16x8 a = *(const bf16x8*)&spool[(prow * 8 + (ch ^ (prow & 7))) * 8];
            acc[mt][0] = __builtin_amdgcn_mfma_f32_16x16x32_bf16(a, b0, acc[mt][0], 0, 0, 0);
            acc[mt][1] = __builtin_amdgcn_mfma_f32_16x16x32_bf16(a, b1, acc[mt][1], 0, 0, 0);
        }
    }
    __syncthreads();   // all sfeat reads done — pool may be rewritten as smlp

    int co0 = wave * 32 + l16, co1 = co0 + 16;
    {
        float sc0 = pg[co0] * rsqrtf(pv[co0] + BN1D_EPS);
        float sb0 = pbb[co0] - pm[co0] * sc0;
        float bs0 = pb[co0];
        float sc1 = pg[co1] * rsqrtf(pv[co1] + BN1D_EPS);
        float sb1 = pbb[co1] - pm[co1] * sc1;
        float bs1 = pb[co1];
#pragma unroll
        for (int mt = 0; mt < 8; ++mt) {
#pragma unroll
            for (int reg = 0; reg < 4; ++reg) {
                int pl = mt * 16 + quad * 4 + reg;
                spool[pl * 128 + co0] = f2bf(fmaxf((acc[mt][0][reg] + bs0) * sc0 + sb0, 0.f));
                spool[pl * 128 + co1] = f2bf(fmaxf((acc[mt][1][reg] + bs1) * sc1 + sb1, 0.f));
            }
        }
    }
    __syncthreads();

    // Phase 2: vectorized gather + blend. task = (point p, chunk c of 8 couts)
#pragma unroll
    for (int it = 0; it < 8; ++it) {
        int t = it * 256 + tid;          // 0..2047
        int p = t >> 4, c = t & 15;
        float a[8];
        const ushort* m = &spool[p * 128 + c * 8];
#pragma unroll
        for (int j = 0; j < 8; ++j) a[j] = bf2f(m[j]);
#pragma unroll
        for (int k = 0; k < 8; ++k) {
            int idx = sidx[p * 8 + k];
            float w = swt[p * 8 + k];
            bf16x8 row = *(const bf16x8*)(g2 + (size_t)idx + c * 8);
#pragma unroll
            for (int j = 0; j < 8; ++j) a[j] += w * bf2f(((u16x8)row)[j]);
        }
        float* o = out + (size_t)(p0 + p) * COUT + c * 8;
        *(float4*)o       = make_float4(a[0], a[1], a[2], a[3]);
        *(float4*)(o + 4) = make_float4(a[4], a[5], a[6], a[7]);
    }

    // coords passthrough (output 1), grid-stride over 512 blocks
    {
        float* dst = out + (size_t)B * N * COUT;
        for (int i = blk * 256 + tid; i < B * N * 3; i += 512 * 256)
            dst[i] = coords[i];
    }
}

// ---------------------------------------------------------------------------
extern "C" void kernel_launch(void* const* d_in, const int* in_sizes, int n_in,
                              void* d_out, int out_size, void* d_ws, size_t ws_size,
                              hipStream_t stream) {
    const float* feats   = (const float*)d_in[0];
    const float* coords  = (const float*)d_in[1];
    const float* conv1_w = (const float*)d_in[2];
    const float* conv1_b = (const float*)d_in[3];
    const float* bn1_g   = (const float*)d_in[4];
    const float* bn1_b   = (const float*)d_in[5];
    const float* bn1_m   = (const float*)d_in[6];
    const float* bn1_v   = (const float*)d_in[7];
    const float* conv2_w = (const float*)d_in[8];
    const float* conv2_b = (const float*)d_in[9];
    const float* bn2_g   = (const float*)d_in[10];
    const float* bn2_b   = (const float*)d_in[11];
    const float* bn2_m   = (const float*)d_in[12];
    const float* bn2_v   = (const float*)d_in[13];
    const float* pw      = (const float*)d_in[14];
    const float* pb      = (const float*)d_in[15];
    const float* pbn_g   = (const float*)d_in[16];
    const float* pbn_b   = (const float*)d_in[17];
    const float* pbn_m   = (const float*)d_in[18];
    const float* pbn_v   = (const float*)d_in[19];

    // Workspace layout
    char* p = (char*)d_ws;
    float* stats = (float*)p;                        p += 1024;
    float* sums  = (float*)p;                        p += (size_t)B * R3 * CIN * 4;
    float* cnt   = (float*)p;                        p += (size_t)B * R3 * 4;
    ushort* gridp = (ushort*)p;                      p += (size_t)B * 2 * RP3 * 32 * 2;
    ushort* g1p   = (ushort*)p;                      p += (size_t)B * 4 * RP3 * 32 * 2;
    ushort* g2b   = (ushort*)p;                      p += (size_t)B * R3 * COUT * 2;
    ushort* wq    = (ushort*)p;                      p += (size_t)164 * 4096 * 2;
    ushort* wq1 = wq;
    ushort* wq2 = wq + 54 * 4096;
    ushort* pwq = wq + 162 * 4096;
    float*  outf  = (float*)d_out;

    // 7 dispatches (~0.6us each measured R20)
    k_prep<<<PREP_ZB + PREP_BB + PREP_WB + PREP_SB, 256, 0, stream>>>(
        coords, conv1_w, conv2_w, pw, sums, gridp, wq, stats);
    k_statsfin<<<4, 256, 0, stream>>>(coords, stats);
    k_scatter<<<(B * N) / 4, 256, 0, stream>>>(coords, feats, stats, sums, cnt);
    k_finalize<<<(B * R3 * CIN) / 256, 256, 0, stream>>>(sums, cnt, gridp);

    k_conv_mfma<CIN, true><<<B * R * (R / 4), 256, 0, stream>>>(
        gridp, wq1, conv1_b, bn1_g, bn1_b, bn1_m, bn1_v, g1p);
    k_conv_mfma<COUT, false><<<B * R * (R / 4), 256, 0, stream>>>(
        g1p, wq2, conv2_b, bn2_g, bn2_b, bn2_m, bn2_v, g2b);

    k_devox<<<(B * N) / 128, 256, 0, stream>>>(coords, feats, stats, g2b, pwq, pb,
                                               pbn_g, pbn_b, pbn_m, pbn_v, outf);
}